// Round 1
// baseline (646.053 us; speedup 1.0000x reference)
//
#include <hip/hip_runtime.h>

// Problem constants
#define D 512
#define H 20
#define V 32000
#define T 1024

typedef unsigned int uint;
typedef unsigned short ushort_t;
typedef __attribute__((ext_vector_type(8))) short short8;
typedef __attribute__((ext_vector_type(4))) float floatx4;

__device__ __forceinline__ unsigned short f2bf(float f) {
    unsigned u = __builtin_bit_cast(unsigned, f);
    u += 0x7fffu + ((u >> 16) & 1u);   // round-to-nearest-even
    return (unsigned short)(u >> 16);
}

__device__ __forceinline__ float tanh_fast(float x) {
    // tanh(x) = 1 - 2/(exp(2x)+1); exp2/rcp saturate correctly at +-inf
    float t = __builtin_amdgcn_exp2f(x * 2.8853900817779268f); // 2*log2(e)
    float r = __builtin_amdgcn_rcpf(t + 1.0f);
    return __builtin_fmaf(-2.0f, r, 1.0f);
}

// ---------------------------------------------------------------- K1: gather
__global__ __launch_bounds__(256) void gather_kernel(const int* __restrict__ tokens,
                                                     const float* __restrict__ embed,
                                                     float* __restrict__ xs) {
    int idx = blockIdx.x * 256 + threadIdx.x;     // float4 units, T*D/4 = 131072
    int row = idx >> 7;                            // D/4 = 128 float4 per row
    int c   = idx & 127;
    float4 v = ((const float4*)(embed + (long)tokens[row] * D))[c];
    ((float4*)xs)[idx] = v;
}

// ---------------------------------------------------- K2: Z = xs @ {wa, wb} (fp32)
__global__ __launch_bounds__(256) void zgemm_kernel(const float* __restrict__ xs,
                                                    const float* __restrict__ wa,
                                                    const float* __restrict__ wb,
                                                    float* __restrict__ z0,
                                                    float* __restrict__ z1) {
    __shared__ float Xs[16 * 68];   // [k][m] transposed, padded
    __shared__ float Ws[16 * 68];   // [k][n] padded
    const int tid = threadIdx.x;
    const int n0 = blockIdx.x * 64, m0 = blockIdx.y * 64;
    const float* Wm = blockIdx.z ? wb : wa;
    float* Z = blockIdx.z ? z1 : z0;
    const int tx = tid & 15, ty = tid >> 4;
    const int xrow = tid >> 2, xkc = (tid & 3) * 4;
    const int wrow = tid >> 4, wc = (tid & 15) * 4;
    float acc[4][4] = {};
    for (int k0 = 0; k0 < D; k0 += 16) {
        float4 xv = *(const float4*)(xs + (long)(m0 + xrow) * D + k0 + xkc);
        float4 wv = *(const float4*)(Wm + (long)(k0 + wrow) * D + n0 + wc);
        Xs[(xkc + 0) * 68 + xrow] = xv.x;
        Xs[(xkc + 1) * 68 + xrow] = xv.y;
        Xs[(xkc + 2) * 68 + xrow] = xv.z;
        Xs[(xkc + 3) * 68 + xrow] = xv.w;
        *(float4*)(Ws + wrow * 68 + wc) = wv;
        __syncthreads();
#pragma unroll
        for (int k = 0; k < 16; k++) {
            float4 a = *(const float4*)(Xs + k * 68 + ty * 4);
            float4 b = *(const float4*)(Ws + k * 68 + tx * 4);
            float av[4] = {a.x, a.y, a.z, a.w};
            float bv[4] = {b.x, b.y, b.z, b.w};
#pragma unroll
            for (int r = 0; r < 4; r++)
#pragma unroll
                for (int c = 0; c < 4; c++)
                    acc[r][c] = __builtin_fmaf(av[r], bv[c], acc[r][c]);
        }
        __syncthreads();
    }
#pragma unroll
    for (int r = 0; r < 4; r++) {
        float4 v = {acc[r][0], acc[r][1], acc[r][2], acc[r][3]};
        *(float4*)(Z + (long)(m0 + ty * 4 + r) * D + n0 + tx * 4) = v;
    }
}

// ------------------------------------------------------------------ K3: scan
// Block = 512 thr (8 waves) handles 2 fw columns. Thread owns fw[ii][j], fw[ii+256][j].
__global__ __launch_bounds__(512) void scan_kernel(const float* __restrict__ z0,
                                                   const float* __restrict__ z1,
                                                   const float* __restrict__ xs,
                                                   const float* __restrict__ fw_init,
                                                   const float* __restrict__ eta_p,
                                                   float* __restrict__ y) {
    const int tid = threadIdx.x;
    const int jj = tid & 1, ii = tid >> 1;
    const int j0 = blockIdx.x * 2;
    const int j = j0 + jj;
    const int wv = tid >> 6, lane = tid & 63;
    __shared__ float part[8 * 8 * 2];
    const float eta = *eta_p;
    float f0 = fw_init[(long)ii * D + j];
    float f1 = fw_init[(long)(ii + 256) * D + j];
    for (int t0 = 0; t0 < T; t0 += 8) {
        float za[8], zb[8], xa[8], xb[8], ez[8];
#pragma unroll
        for (int c = 0; c < 8; c++) {
            const long tr = (long)(t0 + c) * D;
            za[c] = z0[tr + ii];
            zb[c] = z0[tr + ii + 256];
            xa[c] = xs[tr + ii];
            xb[c] = xs[tr + ii + 256];
            ez[c] = z1[tr + j];
        }
        float p[8];
#pragma unroll
        for (int c = 0; c < 8; c++) {
            float e = eta * ez[c];
            f0 = tanh_fast(__builtin_fmaf(e, za[c], f0));
            f1 = tanh_fast(__builtin_fmaf(e, zb[c], f1));
            p[c] = xa[c] * f0 + xb[c] * f1;
        }
        // reduce each p[c] over the 32 ii-lanes of this wave (keep bit0 = jj separate)
#pragma unroll
        for (int c = 0; c < 8; c++) {
            float v = p[c];
#pragma unroll
            for (int m = 2; m <= 32; m <<= 1) v += __shfl_xor(v, m, 64);
            p[c] = v;
        }
        if (lane < 2) {
#pragma unroll
            for (int c = 0; c < 8; c++) part[c * 16 + wv * 2 + lane] = p[c];
        }
        __syncthreads();
        if (tid < 16) {
            int c = tid >> 1, jx = tid & 1;
            float s = 0.f;
#pragma unroll
            for (int w = 0; w < 8; w++) s += part[c * 16 + w * 2 + jx];
            y[(long)(t0 + c) * D + j0 + jx] = s;
        }
        __syncthreads();
    }
}

// ------------------------------------------------- K4: MLP + mix -> bf16 mixed
__global__ __launch_bounds__(64) void mlp_mix_kernel(const float* __restrict__ y,
                                                     const float* __restrict__ xs,
                                                     const float* __restrict__ Aw,
                                                     const float* __restrict__ Ab,
                                                     const float* __restrict__ Bw,
                                                     const float* __restrict__ Bb,
                                                     unsigned short* __restrict__ mixed) {
    const int t = blockIdx.x, lane = threadIdx.x;
    __shared__ float Alds[H * D];    // transposed: [j][d]
    __shared__ float h[H];
    for (int f = lane; f < H * D; f += 64) {
        float v = Aw[f];
        int d = f / H, j = f - d * H;
        Alds[j * D + d] = v;
    }
    float yr[8];
#pragma unroll
    for (int s = 0; s < 8; s++) yr[s] = y[(long)t * D + s * 64 + lane];
    __syncthreads();
    const float sc = 1.0507009873554805f, al = 1.6732632423543772f;
    for (int j = 0; j < H; j++) {
        float a = 0.f;
#pragma unroll
        for (int s = 0; s < 8; s++) a = __builtin_fmaf(yr[s], Alds[j * D + s * 64 + lane], a);
#pragma unroll
        for (int m = 1; m <= 32; m <<= 1) a += __shfl_xor(a, m, 64);
        if (lane == 0) {
            a += Ab[j];
            h[j] = a > 0.f ? sc * a : sc * al * (__expf(a) - 1.f);
        }
    }
    __syncthreads();
#pragma unroll
    for (int s = 0; s < 8; s++) {
        int d = s * 64 + lane;
        float o = Bb[d];
#pragma unroll
        for (int j = 0; j < H; j++) o = __builtin_fmaf(h[j], Bw[j * D + d], o);
        float mx = 0.5f * o + 0.5f * xs[(long)t * D + d];
        mixed[(long)t * D + d] = f2bf(mx);
    }
}

// --------------------------------- K5a: head_w [K][N] f32 -> wt [N][K] bf16
__global__ __launch_bounds__(256) void convert_wt_kernel(const float* __restrict__ head_w,
                                                         unsigned short* __restrict__ wt) {
    __shared__ float tile[64 * 68];
    const int n0 = blockIdx.x * 64, k0 = blockIdx.y * 64;
    const int tid = threadIdx.x;
#pragma unroll
    for (int s = 0; s < 4; s++) {
        int idx4 = s * 256 + tid;            // 1024 float4 slots
        int r = idx4 >> 4, c4 = idx4 & 15;
        float4 v = *(const float4*)(head_w + (long)(k0 + r) * V + n0 + c4 * 4);
        *(float4*)(tile + r * 68 + c4 * 4) = v;
    }
    __syncthreads();
    const int rr = tid >> 2;                 // n within tile
    const int cq = tid & 3;                  // k quarter (16 k's)
    uint u[8];
#pragma unroll
    for (int p = 0; p < 8; p++) {
        float a = tile[(cq * 16 + p * 2 + 0) * 68 + rr];
        float b = tile[(cq * 16 + p * 2 + 1) * 68 + rr];
        u[p] = (uint)f2bf(a) | ((uint)f2bf(b) << 16);
    }
    unsigned short* ob = wt + (long)(n0 + rr) * D + k0 + cq * 16;
    uint4 v0 = {u[0], u[1], u[2], u[3]};
    uint4 v1 = {u[4], u[5], u[6], u[7]};
    *(uint4*)ob = v0;
    *((uint4*)ob + 1) = v1;
}

// ------------------------------------- K5: logits = mixed @ head_w + b (bf16 MFMA)
__global__ __launch_bounds__(256) void head_gemm_kernel(const unsigned short* __restrict__ A,
                                                        const unsigned short* __restrict__ Bt,
                                                        const float* __restrict__ bias,
                                                        float* __restrict__ C) {
    __shared__ unsigned short As[128 * 64];
    __shared__ unsigned short Bs[128 * 64];
    const int tid = threadIdx.x;
    const int mt = blockIdx.x & 7, nt = blockIdx.x >> 3;   // 8 m-tiles grouped for B L2 reuse
    const int m0 = mt * 128, n0 = nt * 128;
    const int wave = tid >> 6, lane = tid & 63;
    const int wm = wave >> 1, wn = wave & 1;
    const int quad = lane >> 4, l15 = lane & 15;
    floatx4 acc[4][4] = {};
    for (int k0 = 0; k0 < D; k0 += 64) {
#pragma unroll
        for (int s = 0; s < 4; s++) {
            int idx = s * 256 + tid;
            int row = idx >> 3, slot = idx & 7;
            int gch = slot ^ (row & 7);                    // XOR swizzle vs LDS slot
            const unsigned short* ga = A + (long)(m0 + row) * D + k0 + gch * 8;
            __builtin_amdgcn_global_load_lds(
                (const __attribute__((address_space(1))) unsigned int*)ga,
                (__attribute__((address_space(3))) unsigned int*)(As + idx * 8), 16, 0, 0);
            const unsigned short* gb = Bt + (long)(n0 + row) * D + k0 + gch * 8;
            __builtin_amdgcn_global_load_lds(
                (const __attribute__((address_space(1))) unsigned int*)gb,
                (__attribute__((address_space(3))) unsigned int*)(Bs + idx * 8), 16, 0, 0);
        }
        __syncthreads();
#pragma unroll
        for (int ks = 0; ks < 2; ks++) {
            short8 af[4], bfr[4];
            int q = ks * 4 + quad;
#pragma unroll
            for (int f = 0; f < 4; f++) {
                int ar = wm * 64 + f * 16 + l15;
                af[f] = *(const short8*)(As + ar * 64 + ((q ^ (ar & 7)) * 8));
                int br = wn * 64 + f * 16 + l15;
                bfr[f] = *(const short8*)(Bs + br * 64 + ((q ^ (br & 7)) * 8));
            }
#pragma unroll
            for (int fr = 0; fr < 4; fr++)
#pragma unroll
                for (int fc = 0; fc < 4; fc++)
                    acc[fr][fc] = __builtin_amdgcn_mfma_f32_16x16x32_bf16(af[fr], bfr[fc],
                                                                          acc[fr][fc], 0, 0, 0);
        }
        __syncthreads();
    }
#pragma unroll
    for (int fc = 0; fc < 4; fc++) {
        int n = n0 + wn * 64 + fc * 16 + l15;
        float b = bias[n];
#pragma unroll
        for (int fr = 0; fr < 4; fr++) {
            int mr = m0 + wm * 64 + fr * 16 + quad * 4;
#pragma unroll
            for (int r = 0; r < 4; r++)
                C[(long)(mr + r) * V + n] = acc[fr][fc][r] + b;
        }
    }
}

// -------------------------------------------- K6: per-row logsumexp + loss_t
__device__ __forceinline__ void lse_upd(float& m, float& s, float v) {
    if (v > m) { s = s * __expf(m - v) + 1.f; m = v; }
    else       { s += __expf(v - m); }
}
__device__ __forceinline__ void lse_comb(float& m, float& s, float m2, float s2) {
    float M = fmaxf(m, m2);
    s = s * __expf(m - M) + s2 * __expf(m2 - M);
    m = M;
}

__global__ __launch_bounds__(256) void loss_rows_kernel(const float* __restrict__ logits,
                                                        const int* __restrict__ targets,
                                                        float* __restrict__ ws_loss) {
    const int t = blockIdx.x, tid = threadIdx.x;
    const float4* row = (const float4*)(logits + (long)t * V);
    float m = -INFINITY, s = 0.f;
    for (int i = tid; i < V / 4; i += 256) {
        float4 v = row[i];
        lse_upd(m, s, v.x); lse_upd(m, s, v.y); lse_upd(m, s, v.z); lse_upd(m, s, v.w);
    }
#pragma unroll
    for (int msk = 1; msk <= 32; msk <<= 1) {
        float m2 = __shfl_xor(m, msk, 64);
        float s2 = __shfl_xor(s, msk, 64);
        lse_comb(m, s, m2, s2);
    }
    __shared__ float sm[4], ss[4];
    if ((tid & 63) == 0) { sm[tid >> 6] = m; ss[tid >> 6] = s; }
    __syncthreads();
    if (tid == 0) {
        float M = sm[0], S = ss[0];
#pragma unroll
        for (int w = 1; w < 4; w++) lse_comb(M, S, sm[w], ss[w]);
        float lse = M + __logf(S);
        float lt = logits[(long)t * V + targets[t]];
        ws_loss[t] = lse - lt;   // -logp(target)
    }
}

__global__ __launch_bounds__(256) void loss_final_kernel(const float* __restrict__ ws_loss,
                                                         float* __restrict__ out) {
    const int tid = threadIdx.x;
    float s = 0.f;
    for (int i = tid; i < T; i += 256) s += ws_loss[i];
#pragma unroll
    for (int m = 1; m <= 32; m <<= 1) s += __shfl_xor(s, m, 64);
    __shared__ float red[4];
    if ((tid & 63) == 0) red[tid >> 6] = s;
    __syncthreads();
    if (tid == 0) out[0] = (red[0] + red[1] + red[2] + red[3]) * (1.f / (float)T);
}

// ------------------------------------------------------------------ launcher
extern "C" void kernel_launch(void* const* d_in, const int* in_sizes, int n_in,
                              void* d_out, int out_size, void* d_ws, size_t ws_size,
                              hipStream_t stream) {
    const int*   tokens  = (const int*)d_in[0];
    const int*   targets = (const int*)d_in[1];
    const float* embed   = (const float*)d_in[2];
    const float* fw_init = (const float*)d_in[3];
    const float* eta     = (const float*)d_in[4];
    const float* wa      = (const float*)d_in[5];
    const float* wb      = (const float*)d_in[6];
    const float* mlp_aw  = (const float*)d_in[7];
    const float* mlp_ab  = (const float*)d_in[8];
    const float* mlp_bw  = (const float*)d_in[9];
    const float* mlp_bb  = (const float*)d_in[10];
    const float* head_w  = (const float*)d_in[11];
    const float* head_b  = (const float*)d_in[12];
    float* out = (float*)d_out;                  // [T*V logits][1 loss]

    char* ws = (char*)d_ws;
    float*          xs      = (float*)(ws + 0);              // 2 MB
    float*          z0      = (float*)(ws + 2097152);        // 2 MB
    float*          z1      = (float*)(ws + 4194304);        // 2 MB
    float*          y       = (float*)(ws + 6291456);        // 2 MB
    unsigned short* mixed   = (unsigned short*)(ws + 8388608);   // 1 MB
    unsigned short* wt      = (unsigned short*)(ws + 9437184);   // 32.75 MB
    float*          ws_loss = (float*)(ws + 42205184);       // 4 KB

    // Independent: head_w transpose+convert (biggest staging pass first)
    convert_wt_kernel<<<dim3(V / 64, D / 64), 256, 0, stream>>>(head_w, wt);
    // xs = embed[tokens]
    gather_kernel<<<(T * D / 4) / 256, 256, 0, stream>>>(tokens, embed, xs);
    // z0 = xs@wa, z1 = xs@wb (fp32)
    zgemm_kernel<<<dim3(D / 64, T / 64, 2), 256, 0, stream>>>(xs, wa, wb, z0, z1);
    // sequential fast-weight scan -> y [T][D]
    scan_kernel<<<D / 2, 512, 0, stream>>>(z0, z1, xs, fw_init, eta, y);
    // mixed = bf16(0.5*mlp(y) + 0.5*xs)
    mlp_mix_kernel<<<T, 64, 0, stream>>>(y, xs, mlp_aw, mlp_ab, mlp_bw, mlp_bb, mixed);
    // logits = mixed @ head_w + head_b
    head_gemm_kernel<<<(T / 128) * (V / 128), 256, 0, stream>>>(mixed, wt, head_b, out);
    // loss
    loss_rows_kernel<<<T, 256, 0, stream>>>(out, targets, ws_loss);
    loss_final_kernel<<<1, 256, 0, stream>>>(ws_loss, out + (long)T * V);
}

// Round 2
// 567.004 us; speedup vs baseline: 1.1394x; 1.1394x over previous
//
#include <hip/hip_runtime.h>

// Problem constants
#define D 512
#define H 20
#define HP 32
#define V 32000
#define T 1024

typedef unsigned int uint;
typedef __attribute__((ext_vector_type(8))) short short8;
typedef __attribute__((ext_vector_type(4))) float floatx4;

__device__ __forceinline__ unsigned short f2bf(float f) {
    unsigned u = __builtin_bit_cast(unsigned, f);
    u += 0x7fffu + ((u >> 16) & 1u);   // round-to-nearest-even
    return (unsigned short)(u >> 16);
}

__device__ __forceinline__ float tanh_fast(float x) {
    // tanh(x) = 1 - 2/(exp(2x)+1); exp2/rcp saturate correctly at +-inf
    float t = __builtin_amdgcn_exp2f(x * 2.8853900817779268f); // 2*log2(e)
    float r = __builtin_amdgcn_rcpf(t + 1.0f);
    return __builtin_fmaf(-2.0f, r, 1.0f);
}

// VALU-pipe cross-lane add via DPP (no LDS pipe!)
template <int CTRL>
__device__ __forceinline__ float dpp_add(float v) {
    int x = __builtin_amdgcn_update_dpp(0, __builtin_bit_cast(int, v), CTRL, 0xf, 0xf, true);
    return v + __builtin_bit_cast(float, x);
}
// reduce 16 contiguous lanes -> all 16 hold the sum
__device__ __forceinline__ float reduce16(float v) {
    v = dpp_add<0xB1>(v);    // quad_perm [1,0,3,2]  (xor 1)
    v = dpp_add<0x4E>(v);    // quad_perm [2,3,0,1]  (xor 2)
    v = dpp_add<0x141>(v);   // row_half_mirror      (xor 7 in 8)
    v = dpp_add<0x140>(v);   // row_mirror           (xor 15 in 16)
    return v;
}

// ---------------------------------------------------------------- K1: gather
__global__ __launch_bounds__(256) void gather_kernel(const int* __restrict__ tokens,
                                                     const float* __restrict__ embed,
                                                     float* __restrict__ xs) {
    int idx = blockIdx.x * 256 + threadIdx.x;     // float4 units, T*D/4 = 131072
    int row = idx >> 7;                            // D/4 = 128 float4 per row
    int c   = idx & 127;
    float4 v = ((const float4*)(embed + (long)tokens[row] * D))[c];
    ((float4*)xs)[idx] = v;
}

// ---------------------------------------------------- K2: Z = xs @ {wa, wb} (fp32)
__global__ __launch_bounds__(256) void zgemm_kernel(const float* __restrict__ xs,
                                                    const float* __restrict__ wa,
                                                    const float* __restrict__ wb,
                                                    float* __restrict__ z0,
                                                    float* __restrict__ z1) {
    __shared__ float Xs[16 * 68];   // [k][m] transposed, padded
    __shared__ float Ws[16 * 68];   // [k][n] padded
    const int tid = threadIdx.x;
    const int n0 = blockIdx.x * 64, m0 = blockIdx.y * 64;
    const float* Wm = blockIdx.z ? wb : wa;
    float* Z = blockIdx.z ? z1 : z0;
    const int tx = tid & 15, ty = tid >> 4;
    const int xrow = tid >> 2, xkc = (tid & 3) * 4;
    const int wrow = tid >> 4, wc = (tid & 15) * 4;
    float acc[4][4] = {};
    for (int k0 = 0; k0 < D; k0 += 16) {
        float4 xv = *(const float4*)(xs + (long)(m0 + xrow) * D + k0 + xkc);
        float4 wv = *(const float4*)(Wm + (long)(k0 + wrow) * D + n0 + wc);
        Xs[(xkc + 0) * 68 + xrow] = xv.x;
        Xs[(xkc + 1) * 68 + xrow] = xv.y;
        Xs[(xkc + 2) * 68 + xrow] = xv.z;
        Xs[(xkc + 3) * 68 + xrow] = xv.w;
        *(float4*)(Ws + wrow * 68 + wc) = wv;
        __syncthreads();
#pragma unroll
        for (int k = 0; k < 16; k++) {
            float4 a = *(const float4*)(Xs + k * 68 + ty * 4);
            float4 b = *(const float4*)(Ws + k * 68 + tx * 4);
            float av[4] = {a.x, a.y, a.z, a.w};
            float bv[4] = {b.x, b.y, b.z, b.w};
#pragma unroll
            for (int r = 0; r < 4; r++)
#pragma unroll
                for (int c = 0; c < 4; c++)
                    acc[r][c] = __builtin_fmaf(av[r], bv[c], acc[r][c]);
        }
        __syncthreads();
    }
#pragma unroll
    for (int r = 0; r < 4; r++) {
        float4 v = {acc[r][0], acc[r][1], acc[r][2], acc[r][3]};
        *(float4*)(Z + (long)(m0 + ty * 4 + r) * D + n0 + tx * 4) = v;
    }
}

// ------------------------------------------------------------------ K3: scan
// 512 blocks x 256 threads. Block owns column j of fw; thread owns fw[tid][j],
// fw[tid+256][j]. Reduction over i: 4 DPP adds (16 lanes) -> tiny LDS hop ->
// 4 DPP adds over 128 threads. One barrier per 8-step chunk, double-buffered.
__global__ __launch_bounds__(256) void scan_kernel(const float* __restrict__ z0,
                                                   const float* __restrict__ z1,
                                                   const float* __restrict__ xs,
                                                   const float* __restrict__ fw_init,
                                                   const float* __restrict__ eta_p,
                                                   float* __restrict__ y) {
    const int tid = threadIdx.x;
    const int j = blockIdx.x;
    const float eta = *eta_p;
    __shared__ float part2[2][8 * 16];     // [buf][c*16 + iiH]
    float f0 = fw_init[(long)tid * D + j];
    float f1 = fw_init[(long)(tid + 256) * D + j];
    float za[8], zb[8], xa[8], xb[8], ez[8];
#pragma unroll
    for (int c = 0; c < 8; c++) {          // preload chunk 0
        const long tr = (long)c * D;
        za[c] = z0[tr + tid];
        zb[c] = z0[tr + tid + 256];
        xa[c] = xs[tr + tid];
        xb[c] = xs[tr + tid + 256];
        ez[c] = z1[tr + j];
    }
    int buf = 0;
    for (int t0 = 0; t0 < T; t0 += 8) {
        float p[8];
#pragma unroll
        for (int c = 0; c < 8; c++) {
            float e = eta * ez[c];
            f0 = tanh_fast(__builtin_fmaf(e, za[c], f0));
            f1 = tanh_fast(__builtin_fmaf(e, zb[c], f1));
            p[c] = xa[c] * f0 + xb[c] * f1;
        }
        if (t0 + 8 < T) {                  // prefetch next chunk during reduce
#pragma unroll
            for (int c = 0; c < 8; c++) {
                const long tr = (long)(t0 + 8 + c) * D;
                za[c] = z0[tr + tid];
                zb[c] = z0[tr + tid + 256];
                xa[c] = xs[tr + tid];
                xb[c] = xs[tr + tid + 256];
                ez[c] = z1[tr + j];
            }
        }
#pragma unroll
        for (int c = 0; c < 8; c++) p[c] = reduce16(p[c]);
        if ((tid & 15) == 0) {
            const int iiH = tid >> 4;
#pragma unroll
            for (int c = 0; c < 8; c++) part2[buf][c * 16 + iiH] = p[c];
        }
        __syncthreads();
        if (tid < 128) {
            const int c = tid >> 4, h = tid & 15;
            float v = part2[buf][c * 16 + h];
            v = reduce16(v);
            if (h == 0) y[(long)(t0 + c) * D + j] = v;
        }
        buf ^= 1;
    }
}

// ------------------------------------------ K4a: h = selu(y @ Aw + Ab)  [T, HP]
__global__ __launch_bounds__(256) void mlp_a_kernel(const float* __restrict__ y,
                                                    const float* __restrict__ Aw,
                                                    const float* __restrict__ Ab,
                                                    float* __restrict__ hbuf) {
    const int gid = blockIdx.x * 256 + threadIdx.x;   // T*32
    const int t = gid >> 5, jj = gid & 31;
    if (jj >= H) return;
    float a = 0.f;
    const float* yr = y + (long)t * D;
#pragma unroll 4
    for (int d = 0; d < D; d++) a = __builtin_fmaf(yr[d], Aw[d * H + jj], a);
    a += Ab[jj];
    const float sc = 1.0507009873554805f, al = 1.6732632423543772f;
    hbuf[t * HP + jj] = a > 0.f ? sc * a : sc * al * (__expf(a) - 1.f);
}

// ----------------------------- K4b: mixed = bf16(0.5*(h@Bw + Bb) + 0.5*xs)
__global__ __launch_bounds__(256) void mlp_b_kernel(const float* __restrict__ hbuf,
                                                    const float* __restrict__ xs,
                                                    const float* __restrict__ Bw,
                                                    const float* __restrict__ Bb,
                                                    unsigned short* __restrict__ mixed) {
    const int gid = blockIdx.x * 256 + threadIdx.x;   // T*D
    const int t = gid >> 9, d = gid & 511;
    float o = Bb[d];
    const float* hr = hbuf + (long)t * HP;
#pragma unroll
    for (int jj = 0; jj < H; jj++) o = __builtin_fmaf(hr[jj], Bw[jj * D + d], o);
    mixed[gid] = f2bf(0.5f * o + 0.5f * xs[gid]);
}

// --------------------------------- K5a: head_w [K][N] f32 -> wt [N][K] bf16
__global__ __launch_bounds__(256) void convert_wt_kernel(const float* __restrict__ head_w,
                                                         unsigned short* __restrict__ wt) {
    __shared__ float tile[64 * 68];
    const int n0 = blockIdx.x * 64, k0 = blockIdx.y * 64;
    const int tid = threadIdx.x;
#pragma unroll
    for (int s = 0; s < 4; s++) {
        int idx4 = s * 256 + tid;            // 1024 float4 slots
        int r = idx4 >> 4, c4 = idx4 & 15;
        float4 v = *(const float4*)(head_w + (long)(k0 + r) * V + n0 + c4 * 4);
        *(float4*)(tile + r * 68 + c4 * 4) = v;
    }
    __syncthreads();
    const int rr = tid >> 2;                 // n within tile
    const int cq = tid & 3;                  // k quarter (16 k's)
    uint u[8];
#pragma unroll
    for (int p = 0; p < 8; p++) {
        float a = tile[(cq * 16 + p * 2 + 0) * 68 + rr];
        float b = tile[(cq * 16 + p * 2 + 1) * 68 + rr];
        u[p] = (uint)f2bf(a) | ((uint)f2bf(b) << 16);
    }
    unsigned short* ob = wt + (long)(n0 + rr) * D + k0 + cq * 16;
    uint4 v0 = {u[0], u[1], u[2], u[3]};
    uint4 v1 = {u[4], u[5], u[6], u[7]};
    *(uint4*)ob = v0;
    *((uint4*)ob + 1) = v1;
}

// ------------------------------------- K5: logits = mixed @ head_w + b (bf16 MFMA)
__global__ __launch_bounds__(256) void head_gemm_kernel(const unsigned short* __restrict__ A,
                                                        const unsigned short* __restrict__ Bt,
                                                        const float* __restrict__ bias,
                                                        float* __restrict__ C) {
    __shared__ unsigned short As[128 * 64];
    __shared__ unsigned short Bs[128 * 64];
    const int tid = threadIdx.x;
    const int mt = blockIdx.x & 7, nt = blockIdx.x >> 3;   // 8 m-tiles grouped for B L2 reuse
    const int m0 = mt * 128, n0 = nt * 128;
    const int wave = tid >> 6, lane = tid & 63;
    const int wm = wave >> 1, wn = wave & 1;
    const int quad = lane >> 4, l15 = lane & 15;
    floatx4 acc[4][4] = {};
    for (int k0 = 0; k0 < D; k0 += 64) {
#pragma unroll
        for (int s = 0; s < 4; s++) {
            int idx = s * 256 + tid;
            int row = idx >> 3, slot = idx & 7;
            int gch = slot ^ (row & 7);                    // XOR swizzle vs LDS slot
            const unsigned short* ga = A + (long)(m0 + row) * D + k0 + gch * 8;
            __builtin_amdgcn_global_load_lds(
                (const __attribute__((address_space(1))) unsigned int*)ga,
                (__attribute__((address_space(3))) unsigned int*)(As + idx * 8), 16, 0, 0);
            const unsigned short* gb = Bt + (long)(n0 + row) * D + k0 + gch * 8;
            __builtin_amdgcn_global_load_lds(
                (const __attribute__((address_space(1))) unsigned int*)gb,
                (__attribute__((address_space(3))) unsigned int*)(Bs + idx * 8), 16, 0, 0);
        }
        __syncthreads();
#pragma unroll
        for (int ks = 0; ks < 2; ks++) {
            short8 af[4], bfr[4];
            int q = ks * 4 + quad;
#pragma unroll
            for (int f = 0; f < 4; f++) {
                int ar = wm * 64 + f * 16 + l15;
                af[f] = *(const short8*)(As + ar * 64 + ((q ^ (ar & 7)) * 8));
                int br = wn * 64 + f * 16 + l15;
                bfr[f] = *(const short8*)(Bs + br * 64 + ((q ^ (br & 7)) * 8));
            }
#pragma unroll
            for (int fr = 0; fr < 4; fr++)
#pragma unroll
                for (int fc = 0; fc < 4; fc++)
                    acc[fr][fc] = __builtin_amdgcn_mfma_f32_16x16x32_bf16(af[fr], bfr[fc],
                                                                          acc[fr][fc], 0, 0, 0);
        }
        __syncthreads();
    }
#pragma unroll
    for (int fc = 0; fc < 4; fc++) {
        int n = n0 + wn * 64 + fc * 16 + l15;
        float b = bias[n];
#pragma unroll
        for (int fr = 0; fr < 4; fr++) {
            int mr = m0 + wm * 64 + fr * 16 + quad * 4;
#pragma unroll
            for (int r = 0; r < 4; r++)
                C[(long)(mr + r) * V + n] = acc[fr][fc][r] + b;
        }
    }
}

// -------------------------------------------- K6: per-row logsumexp + loss_t
__device__ __forceinline__ void lse_upd(float& m, float& s, float v) {
    if (v > m) { s = s * __expf(m - v) + 1.f; m = v; }
    else       { s += __expf(v - m); }
}
__device__ __forceinline__ void lse_comb(float& m, float& s, float m2, float s2) {
    float M = fmaxf(m, m2);
    s = s * __expf(m - M) + s2 * __expf(m2 - M);
    m = M;
}

__global__ __launch_bounds__(256) void loss_rows_kernel(const float* __restrict__ logits,
                                                        const int* __restrict__ targets,
                                                        float* __restrict__ ws_loss) {
    const int t = blockIdx.x, tid = threadIdx.x;
    const float4* row = (const float4*)(logits + (long)t * V);
    float m = -INFINITY, s = 0.f;
    for (int i = tid; i < V / 4; i += 256) {
        float4 v = row[i];
        lse_upd(m, s, v.x); lse_upd(m, s, v.y); lse_upd(m, s, v.z); lse_upd(m, s, v.w);
    }
#pragma unroll
    for (int msk = 1; msk <= 32; msk <<= 1) {
        float m2 = __shfl_xor(m, msk, 64);
        float s2 = __shfl_xor(s, msk, 64);
        lse_comb(m, s, m2, s2);
    }
    __shared__ float sm[4], ss[4];
    if ((tid & 63) == 0) { sm[tid >> 6] = m; ss[tid >> 6] = s; }
    __syncthreads();
    if (tid == 0) {
        float M = sm[0], S = ss[0];
#pragma unroll
        for (int w = 1; w < 4; w++) lse_comb(M, S, sm[w], ss[w]);
        float lse = M + __logf(S);
        float lt = logits[(long)t * V + targets[t]];
        ws_loss[t] = lse - lt;   // -logp(target)
    }
}

__global__ __launch_bounds__(256) void loss_final_kernel(const float* __restrict__ ws_loss,
                                                         float* __restrict__ out) {
    const int tid = threadIdx.x;
    float s = 0.f;
    for (int i = tid; i < T; i += 256) s += ws_loss[i];
#pragma unroll
    for (int m = 1; m <= 32; m <<= 1) s += __shfl_xor(s, m, 64);
    __shared__ float red[4];
    if ((tid & 63) == 0) red[tid >> 6] = s;
    __syncthreads();
    if (tid == 0) out[0] = (red[0] + red[1] + red[2] + red[3]) * (1.f / (float)T);
}

// ------------------------------------------------------------------ launcher
extern "C" void kernel_launch(void* const* d_in, const int* in_sizes, int n_in,
                              void* d_out, int out_size, void* d_ws, size_t ws_size,
                              hipStream_t stream) {
    const int*   tokens  = (const int*)d_in[0];
    const int*   targets = (const int*)d_in[1];
    const float* embed   = (const float*)d_in[2];
    const float* fw_init = (const float*)d_in[3];
    const float* eta     = (const float*)d_in[4];
    const float* wa      = (const float*)d_in[5];
    const float* wb      = (const float*)d_in[6];
    const float* mlp_aw  = (const float*)d_in[7];
    const float* mlp_ab  = (const float*)d_in[8];
    const float* mlp_bw  = (const float*)d_in[9];
    const float* mlp_bb  = (const float*)d_in[10];
    const float* head_w  = (const float*)d_in[11];
    const float* head_b  = (const float*)d_in[12];
    float* out = (float*)d_out;                  // [T*V logits][1 loss]

    char* ws = (char*)d_ws;
    float*          xs      = (float*)(ws + 0);                  // 2 MB
    float*          z0      = (float*)(ws + 2097152);            // 2 MB
    float*          z1      = (float*)(ws + 4194304);            // 2 MB
    float*          y       = (float*)(ws + 6291456);            // 2 MB
    unsigned short* mixed   = (unsigned short*)(ws + 8388608);   // 1 MB
    unsigned short* wt      = (unsigned short*)(ws + 9437184);   // 32.75 MB
    float*          ws_loss = (float*)(ws + 42205184);           // 4 KB
    float*          hbuf    = (float*)(ws + 42209280);           // 128 KB

    // Independent: head_w transpose+convert (biggest staging pass first)
    convert_wt_kernel<<<dim3(V / 64, D / 64), 256, 0, stream>>>(head_w, wt);
    // xs = embed[tokens]
    gather_kernel<<<(T * D / 4) / 256, 256, 0, stream>>>(tokens, embed, xs);
    // z0 = xs@wa, z1 = xs@wb (fp32)
    zgemm_kernel<<<dim3(D / 64, T / 64, 2), 256, 0, stream>>>(xs, wa, wb, z0, z1);
    // sequential fast-weight scan -> y [T][D]
    scan_kernel<<<D, 256, 0, stream>>>(z0, z1, xs, fw_init, eta, y);
    // h = selu(y@Aw+Ab); mixed = bf16(0.5*(h@Bw+Bb) + 0.5*xs)
    mlp_a_kernel<<<(T * HP) / 256, 256, 0, stream>>>(y, mlp_aw, mlp_ab, hbuf);
    mlp_b_kernel<<<(T * D) / 256, 256, 0, stream>>>(hbuf, xs, mlp_bw, mlp_bb, mixed);
    // logits = mixed @ head_w + head_b
    head_gemm_kernel<<<(T / 128) * (V / 128), 256, 0, stream>>>(mixed, wt, head_b, out);
    // loss
    loss_rows_kernel<<<T, 256, 0, stream>>>(out, targets, ws_loss);
    loss_final_kernel<<<1, 256, 0, stream>>>(ws_loss, out + (long)T * V);
}